// Round 1
// baseline (79.548 us; speedup 1.0000x reference)
//
#include <hip/hip_runtime.h>
#include <math.h>

#define BATCH   262144
#define NASSETS 128
#define CHUNK   128
#define NCHUNK  (BATCH / CHUNK)   // 2048
#define ETA     0.01
#define CDECAY  0.99
#define EPS     1e-8

// K1: per-chunk (128 rows): compute R[t] = dot(weights[t], returns[t]) with
// coalesced float4 loads, then the chunk's decay-weighted sums
//   S_A = eta * sum_k c^(L-1-k) * r_k,  S_B = eta * sum_k c^(L-1-k) * r_k^2
__global__ __launch_bounds__(256) void k_rows_chunks(
    const float* __restrict__ W, const float* __restrict__ X,
    float* __restrict__ R, double* __restrict__ SA, double* __restrict__ SB) {
  __shared__ float  rsh[CHUNK];
  __shared__ double redA[4], redB[4];
  const int chunk = blockIdx.x;
  const int tid   = threadIdx.x;
  const int wave  = tid >> 6;        // 0..3
  const int lane  = tid & 63;
  const int sub   = lane >> 5;       // which row of the pair
  const int col   = lane & 31;       // float4 column 0..31
  const size_t rowbase = (size_t)chunk * CHUNK + (size_t)wave * 32;

  #pragma unroll 4
  for (int p = 0; p < 16; ++p) {
    size_t row = rowbase + (size_t)(p * 2 + sub);
    float4 w4 = reinterpret_cast<const float4*>(W)[row * 32 + col];
    float4 x4 = reinterpret_cast<const float4*>(X)[row * 32 + col];
    float s = w4.x * x4.x + w4.y * x4.y + w4.z * x4.z + w4.w * x4.w;
    // reduce across the 32 lanes covering this row (xor masks stay in-group)
    s += __shfl_xor(s, 16, 64);
    s += __shfl_xor(s, 8, 64);
    s += __shfl_xor(s, 4, 64);
    s += __shfl_xor(s, 2, 64);
    s += __shfl_xor(s, 1, 64);
    if (col == 0) rsh[wave * 32 + p * 2 + sub] = s;
  }
  __syncthreads();

  double sA = 0.0, sB = 0.0;
  if (tid < CHUNK) {
    float rv = rsh[tid];
    R[(size_t)chunk * CHUNK + tid] = rv;
    double r = (double)rv;
    double wgt = ETA * pow(CDECAY, (double)(CHUNK - 1 - tid));
    sA = wgt * r;
    sB = wgt * r * r;
  }
  // block reduce (waves 2,3 contribute zeros)
  sA += __shfl_xor(sA, 32, 64); sB += __shfl_xor(sB, 32, 64);
  sA += __shfl_xor(sA, 16, 64); sB += __shfl_xor(sB, 16, 64);
  sA += __shfl_xor(sA,  8, 64); sB += __shfl_xor(sB,  8, 64);
  sA += __shfl_xor(sA,  4, 64); sB += __shfl_xor(sB,  4, 64);
  sA += __shfl_xor(sA,  2, 64); sB += __shfl_xor(sB,  2, 64);
  sA += __shfl_xor(sA,  1, 64); sB += __shfl_xor(sB,  1, 64);
  if (lane == 0) { redA[wave] = sA; redB[wave] = sB; }
  __syncthreads();
  if (tid == 0) {
    SA[chunk] = redA[0] + redA[1] + redA[2] + redA[3];
    SB[chunk] = redB[0] + redB[1] + redB[2] + redB[3];
  }
}

// K2: one wave scans the 2048 chunk carries.
// A_in(j+1) = m * A_in(j) + S_A(j), m = c^CHUNK. Homogeneous A0/B0 term
// added analytically as A0 * c^(CHUNK*j) (underflow to 0 = exact decay).
__global__ void k_scan(const double* __restrict__ SA, const double* __restrict__ SB,
                       const float* __restrict__ A0p, const float* __restrict__ B0p,
                       double* __restrict__ CA, double* __restrict__ CB) {
  const int lane = threadIdx.x;                 // 64 threads
  const int PER  = NCHUNK / 64;                 // 32 chunks per lane
  const double m = pow(CDECAY, (double)CHUNK);  // c^128
  const int base = lane * PER;

  // thread-local composed sum over its 32 chunks
  double aT = 0.0, bT = 0.0;
  for (int i = 0; i < PER; ++i) {
    aT = m * aT + SA[base + i];
    bT = m * bT + SB[base + i];
  }
  // Hillis-Steele inclusive scan across lanes; multiplier squares each pass
  double M = pow(CDECAY, (double)(CHUNK * PER));  // c^4096
  double ai = aT, bi = bT, f = M;
  for (int d = 1; d < 64; d <<= 1) {
    double au = __shfl_up(ai, d, 64);
    double bu = __shfl_up(bi, d, 64);
    if (lane >= d) { ai += f * au; bi += f * bu; }
    f *= f;
  }
  // exclusive: carry entering this lane's block
  double aIn = __shfl_up(ai, 1, 64);
  double bIn = __shfl_up(bi, 1, 64);
  if (lane == 0) { aIn = 0.0; bIn = 0.0; }

  const double A0v = (double)A0p[0];
  const double B0v = (double)B0p[0];
  double A = aIn, B = bIn;
  double h = pow(CDECAY, (double)CHUNK * (double)base);
  for (int i = 0; i < PER; ++i) {
    int j = base + i;
    CA[j] = A + A0v * h;
    CB[j] = B + B0v * h;
    A = m * A + SA[j];
    B = m * B + SB[j];
    h *= m;
  }
}

// K3: one thread per chunk replays the exact reference recurrence in f64
// from its carry, accumulating sum of D. Loop-carried dep = 2 FMAs only.
__global__ __launch_bounds__(256) void k_dsr(
    const float* __restrict__ R, const double* __restrict__ CA,
    const double* __restrict__ CB, double* __restrict__ acc) {
  const int j = blockIdx.x * blockDim.x + threadIdx.x;
  double sum = 0.0;
  if (j < NCHUNK) {
    double A = CA[j], B = CB[j];
    const float* r = R + (size_t)j * CHUNK;
    for (int k = 0; k < CHUNK; ++k) {
      double rv = (double)r[k];
      double dA = ETA * (rv - A);
      double dB = ETA * (rv * rv - B);
      double var = B - A * A;
      var = var > EPS ? var : EPS;
      double D = (B * dA - 0.5 * A * dB) / (var * sqrt(var));
      sum += D;
      A += dA;
      B += dB;
    }
  }
  sum += __shfl_xor(sum, 32, 64);
  sum += __shfl_xor(sum, 16, 64);
  sum += __shfl_xor(sum,  8, 64);
  sum += __shfl_xor(sum,  4, 64);
  sum += __shfl_xor(sum,  2, 64);
  sum += __shfl_xor(sum,  1, 64);
  __shared__ double red[4];
  const int wave = threadIdx.x >> 6, lane = threadIdx.x & 63;
  if (lane == 0) red[wave] = sum;
  __syncthreads();
  if (threadIdx.x == 0) atomicAdd(acc, red[0] + red[1] + red[2] + red[3]);
}

__global__ void k_fin(const double* __restrict__ acc, float* __restrict__ out) {
  out[0] = (float)(-acc[0] / (double)BATCH);
}

extern "C" void kernel_launch(void* const* d_in, const int* in_sizes, int n_in,
                              void* d_out, int out_size, void* d_ws, size_t ws_size,
                              hipStream_t stream) {
  const float* W  = (const float*)d_in[0];
  const float* X  = (const float*)d_in[1];
  const float* A0 = (const float*)d_in[2];
  const float* B0 = (const float*)d_in[3];

  char* ws = (char*)d_ws;
  float*  R  = (float*)ws;                                // 1 MB
  double* SA = (double*)(ws + (size_t)BATCH * 4);         // 16 KB
  double* SB = SA + NCHUNK;
  double* CA = SB + NCHUNK;
  double* CB = CA + NCHUNK;
  double* acc = CB + NCHUNK;

  hipMemsetAsync(acc, 0, sizeof(double), stream);
  k_rows_chunks<<<NCHUNK, 256, 0, stream>>>(W, X, R, SA, SB);
  k_scan<<<1, 64, 0, stream>>>(SA, SB, A0, B0, CA, CB);
  k_dsr<<<NCHUNK / 256, 256, 0, stream>>>(R, CA, CB, acc);
  k_fin<<<1, 1, 0, stream>>>(acc, (float*)d_out);
}

// Round 2
// 76.646 us; speedup vs baseline: 1.0379x; 1.0379x over previous
//
#include <hip/hip_runtime.h>
#include <math.h>

#define BATCH     262144
#define NASSETS   128
#define TILE_ROWS 128                    // rows per K1 block
#define NBLK      (BATCH / TILE_ROWS)    // 2048
#define SCHUNK    32                     // scan / replay chunk
#define NSC       (BATCH / SCHUNK)       // 8192
#define ETA       0.01
#define CDECAY    0.99
#define EPS       1e-8
#define LPAD      33                     // 128-row LDS tile, padded stride

// K1: streaming dot products, no shfl in the hot loop.
// Phase 1: 16 fully independent float4-pair loads per thread; 4-elem dot;
//          ds_write into padded transpose buffer. Max MLP.
// Phase 2: thread t (<128) sums its row's 32 partials from LDS (2-way bank
//          aliasing = free on CDNA4), writes R, then the 32-row scan-carry
//          sums SA/SB via in-group shfl (off the memory path).
__global__ __launch_bounds__(256) void k_rows(
    const float* __restrict__ W, const float* __restrict__ X,
    float* __restrict__ R, double* __restrict__ SA, double* __restrict__ SB) {
  __shared__ float part[TILE_ROWS * LPAD];
  const int t   = threadIdx.x;
  const int blk = blockIdx.x;
  const float4* W4 = reinterpret_cast<const float4*>(W) + (size_t)blk * (TILE_ROWS * NASSETS / 4);
  const float4* X4 = reinterpret_cast<const float4*>(X) + (size_t)blk * (TILE_ROWS * NASSETS / 4);

  #pragma unroll
  for (int p = 0; p < 16; ++p) {
    int idx = p * 256 + t;              // flat float4 index in tile
    float4 w4 = W4[idx];
    float4 x4 = X4[idx];
    float s = w4.x * x4.x + w4.y * x4.y + w4.z * x4.z + w4.w * x4.w;
    part[(idx >> 5) * LPAD + (idx & 31)] = s;   // row = idx>>5, col4 = idx&31
  }
  __syncthreads();

  if (t < TILE_ROWS) {
    float sum = 0.f;
    #pragma unroll
    for (int j = 0; j < 32; ++j) sum += part[t * LPAD + j];
    R[(size_t)blk * TILE_ROWS + t] = sum;

    // scan-carry contribution for this row's 32-group
    double r   = (double)sum;
    double wgt = ETA * pow(CDECAY, (double)(SCHUNK - 1 - (t & (SCHUNK - 1))));
    double sA = wgt * r;
    double sB = wgt * r * r;
    // reduce within each 32-lane group (masks <32 stay in-group)
    sA += __shfl_xor(sA, 16, 64); sB += __shfl_xor(sB, 16, 64);
    sA += __shfl_xor(sA,  8, 64); sB += __shfl_xor(sB,  8, 64);
    sA += __shfl_xor(sA,  4, 64); sB += __shfl_xor(sB,  4, 64);
    sA += __shfl_xor(sA,  2, 64); sB += __shfl_xor(sB,  2, 64);
    sA += __shfl_xor(sA,  1, 64); sB += __shfl_xor(sB,  1, 64);
    if ((t & 31) == 0) {
      int g = t >> 5;                   // 0..3
      SA[(size_t)blk * 4 + g] = sA;
      SB[(size_t)blk * 4 + g] = sB;
    }
  }
}

// K2: one wave scans the 8192 32-row carries.
// A_in(j+1) = m*A_in(j) + S_A(j), m = c^SCHUNK. Homogeneous A0/B0 term added
// analytically as A0 * c^(SCHUNK*j) (f64 underflow to 0 = genuinely negligible).
__global__ void k_scan(const double* __restrict__ SA, const double* __restrict__ SB,
                       const float* __restrict__ A0p, const float* __restrict__ B0p,
                       double* __restrict__ CA, double* __restrict__ CB) {
  const int lane = threadIdx.x;                  // 64 threads
  const int PER  = NSC / 64;                     // 128 chunks per lane
  const double m = pow(CDECAY, (double)SCHUNK);  // c^32
  const int base = lane * PER;

  double aT = 0.0, bT = 0.0;
  for (int i = 0; i < PER; ++i) {
    aT = m * aT + SA[base + i];
    bT = m * bT + SB[base + i];
  }
  // Hillis-Steele inclusive scan across lanes; multiplier squares each pass
  double M = pow(CDECAY, (double)(SCHUNK * PER));  // c^4096 ~ 1.3e-18 (repr.)
  double ai = aT, bi = bT, f = M;
  for (int d = 1; d < 64; d <<= 1) {
    double au = __shfl_up(ai, d, 64);
    double bu = __shfl_up(bi, d, 64);
    if (lane >= d) { ai += f * au; bi += f * bu; }
    f *= f;
  }
  double aIn = __shfl_up(ai, 1, 64);
  double bIn = __shfl_up(bi, 1, 64);
  if (lane == 0) { aIn = 0.0; bIn = 0.0; }

  const double A0v = (double)A0p[0];
  const double B0v = (double)B0p[0];
  double A = aIn, B = bIn;
  double h = pow(CDECAY, (double)SCHUNK * (double)base);
  for (int i = 0; i < PER; ++i) {
    int j = base + i;
    CA[j] = A + A0v * h;
    CB[j] = B + B0v * h;
    A = m * A + SA[j];
    B = m * B + SB[j];
    h *= m;
  }
}

// K3: one thread per 32-row chunk replays the exact recurrence in f64 from its
// carry. 8192 threads; serial chain is only 2 f64 FMAs/iter.
__global__ __launch_bounds__(256) void k_dsr(
    const float* __restrict__ R, const double* __restrict__ CA,
    const double* __restrict__ CB, double* __restrict__ acc) {
  const int j = blockIdx.x * blockDim.x + threadIdx.x;   // 0..8191
  double A = CA[j], B = CB[j];
  const float* r = R + (size_t)j * SCHUNK;
  double sum = 0.0;
  #pragma unroll
  for (int k = 0; k < SCHUNK; ++k) {
    double rv = (double)r[k];
    double dA = ETA * (rv - A);
    double dB = ETA * (rv * rv - B);
    double var = B - A * A;
    var = var > EPS ? var : EPS;
    sum += (B * dA - 0.5 * A * dB) / (var * sqrt(var));
    A += dA;
    B += dB;
  }
  sum += __shfl_xor(sum, 32, 64);
  sum += __shfl_xor(sum, 16, 64);
  sum += __shfl_xor(sum,  8, 64);
  sum += __shfl_xor(sum,  4, 64);
  sum += __shfl_xor(sum,  2, 64);
  sum += __shfl_xor(sum,  1, 64);
  __shared__ double red[4];
  const int wave = threadIdx.x >> 6, lane = threadIdx.x & 63;
  if (lane == 0) red[wave] = sum;
  __syncthreads();
  if (threadIdx.x == 0) atomicAdd(acc, red[0] + red[1] + red[2] + red[3]);
}

__global__ void k_fin(const double* __restrict__ acc, float* __restrict__ out) {
  out[0] = (float)(-acc[0] / (double)BATCH);
}

extern "C" void kernel_launch(void* const* d_in, const int* in_sizes, int n_in,
                              void* d_out, int out_size, void* d_ws, size_t ws_size,
                              hipStream_t stream) {
  const float* W  = (const float*)d_in[0];
  const float* X  = (const float*)d_in[1];
  const float* A0 = (const float*)d_in[2];
  const float* B0 = (const float*)d_in[3];

  char* ws = (char*)d_ws;
  float*  R  = (float*)ws;                                 // 1 MB
  double* SA = (double*)(ws + (size_t)BATCH * 4);          // 64 KB each
  double* SB = SA + NSC;
  double* CA = SB + NSC;
  double* CB = CA + NSC;
  double* acc = CB + NSC;

  hipMemsetAsync(acc, 0, sizeof(double), stream);
  k_rows<<<NBLK, 256, 0, stream>>>(W, X, R, SA, SB);
  k_scan<<<1, 64, 0, stream>>>(SA, SB, A0, B0, CA, CB);
  k_dsr<<<NSC / 256, 256, 0, stream>>>(R, CA, CB, acc);
  k_fin<<<1, 1, 0, stream>>>(acc, (float*)d_out);
}

// Round 3
// 59.199 us; speedup vs baseline: 1.3437x; 1.2947x over previous
//
#include <hip/hip_runtime.h>
#include <math.h>

#define BATCH     262144
#define NASSETS   128
#define TILE_ROWS 128                    // rows per K1 block
#define NBLK      (BATCH / TILE_ROWS)    // 2048
#define SCHUNK    32                     // scan / replay chunk
#define NSC       (BATCH / SCHUNK)       // 8192
#define ETA       0.01
#define CDECAY    0.99
#define EPS       1e-8
#define LPAD      33

// Transposed carry layout: chunk c stored at (c&31)*256 + (c>>5).
// k_rows scatter-writes 8 doubles/block; k_scan reads/writes fully coalesced.
__device__ __forceinline__ int tpos(int c) { return (c & 31) * 256 + (c >> 5); }

__global__ __launch_bounds__(256) void k_rows(
    const float* __restrict__ W, const float* __restrict__ X,
    float* __restrict__ R, double* __restrict__ SAt, double* __restrict__ SBt) {
  __shared__ float part[TILE_ROWS * LPAD];
  const int t   = threadIdx.x;
  const int blk = blockIdx.x;
  const float4* W4 = reinterpret_cast<const float4*>(W) + (size_t)blk * 4096;
  const float4* X4 = reinterpret_cast<const float4*>(X) + (size_t)blk * 4096;

  // Phase 1: 4 batches; each stages 8 loads (4 W-pairs + 4 X-pairs) before
  // computing, so 8 independent 1KB wave-loads are in flight at a time.
  #pragma unroll
  for (int b = 0; b < 4; ++b) {
    const int i0 = b * 1024 + t;
    float4 w0 = W4[i0];       float4 w1 = W4[i0 + 256];
    float4 w2 = W4[i0 + 512]; float4 w3 = W4[i0 + 768];
    float4 x0 = X4[i0];       float4 x1 = X4[i0 + 256];
    float4 x2 = X4[i0 + 512]; float4 x3 = X4[i0 + 768];
    const int r0 = (i0 >> 5), col = (i0 & 31);
    part[(r0 +  0) * LPAD + col] = w0.x*x0.x + w0.y*x0.y + w0.z*x0.z + w0.w*x0.w;
    part[(r0 +  8) * LPAD + col] = w1.x*x1.x + w1.y*x1.y + w1.z*x1.z + w1.w*x1.w;
    part[(r0 + 16) * LPAD + col] = w2.x*x2.x + w2.y*x2.y + w2.z*x2.z + w2.w*x2.w;
    part[(r0 + 24) * LPAD + col] = w3.x*x3.x + w3.y*x3.y + w3.z*x3.z + w3.w*x3.w;
  }
  __syncthreads();

  // Phase 2: 128 threads sum their row; group carries via shfl (no pow).
  if (t < TILE_ROWS) {
    float sum = 0.f;
    #pragma unroll
    for (int j = 0; j < 32; ++j) sum += part[t * LPAD + j];
    R[(size_t)blk * TILE_ROWS + t] = sum;

    const int e = 31 - (t & 31);            // wgt = ETA * c^e via square-select
    const double c1 = CDECAY, c2 = c1*c1, c4 = c2*c2, c8 = c4*c4, c16 = c8*c8;
    double wgt = ETA;
    if (e & 1)  wgt *= c1;
    if (e & 2)  wgt *= c2;
    if (e & 4)  wgt *= c4;
    if (e & 8)  wgt *= c8;
    if (e & 16) wgt *= c16;
    const double r = (double)sum;
    double sA = wgt * r, sB = wgt * r * r;
    sA += __shfl_xor(sA, 16, 64); sB += __shfl_xor(sB, 16, 64);
    sA += __shfl_xor(sA,  8, 64); sB += __shfl_xor(sB,  8, 64);
    sA += __shfl_xor(sA,  4, 64); sB += __shfl_xor(sB,  4, 64);
    sA += __shfl_xor(sA,  2, 64); sB += __shfl_xor(sB,  2, 64);
    sA += __shfl_xor(sA,  1, 64); sB += __shfl_xor(sB,  1, 64);
    if ((t & 31) == 0) {
      const int c = blk * 4 + (t >> 5);
      SAt[tpos(c)] = sA;
      SBt[tpos(c)] = sB;
    }
  }
}

// K2: 256 threads, one block. Lane l owns chunks [32l, 32l+32).
// Coalesced via transposed layout. Two-level scan: wave Hillis-Steele +
// serial cross-wave combine. Also zero-inits acc/cnt for k_dsr.
__global__ __launch_bounds__(256) void k_scan(
    const double* __restrict__ SAt, const double* __restrict__ SBt,
    const float* __restrict__ A0p, const float* __restrict__ B0p,
    double* __restrict__ CAt, double* __restrict__ CBt,
    double* __restrict__ acc, unsigned* __restrict__ cnt) {
  const int l = threadIdx.x;            // 0..255
  const int lw = l & 63, w = l >> 6;
  __shared__ double wtot[4], wcar[4];

  double m = CDECAY;                    // -> c^32 (per-chunk factor)
  #pragma unroll
  for (int q = 0; q < 5; ++q) m = m * m;
  double g = m;                         // -> m^32 = c^1024 (per-lane factor)
  #pragma unroll
  for (int q = 0; q < 5; ++q) g = g * g;
  double F = g;                         // -> g^64 (per-wave factor)
  #pragma unroll
  for (int q = 0; q < 6; ++q) F = F * F;
  double glw = 1.0, gl = 1.0, p2 = g;   // g^lw and g^l via bit-select
  #pragma unroll
  for (int b = 0; b < 8; ++b) {
    if (lw & (1 << b)) glw *= p2;
    if (l  & (1 << b)) gl  *= p2;
    p2 = p2 * p2;
  }

  #pragma unroll 1
  for (int arr = 0; arr < 2; ++arr) {
    const double* St = arr ? SBt : SAt;
    double*       Ct = arr ? CBt : CAt;
    const double init0 = arr ? (double)B0p[0] : (double)A0p[0];

    double y = 0.0;                     // compose this lane's 32 chunks
    for (int i = 0; i < 32; ++i) y = m * y + St[i * 256 + l];

    double s = y, f = g;                // wave-level scan (factor g, squares)
    #pragma unroll
    for (int d = 1; d < 64; d <<= 1) {
      double u = __shfl_up(s, d, 64);
      if (lw >= d) s += f * u;
      f *= f;
    }
    if (lw == 63) wtot[w] = s;
    __syncthreads();
    if (l == 0) {
      double Wc = 0.0;
      for (int ww = 0; ww < 4; ++ww) { wcar[ww] = Wc; Wc = wtot[ww] + F * Wc; }
    }
    __syncthreads();
    double aIn = __shfl_up(s, 1, 64);
    if (lw == 0) aIn = 0.0;
    double A = aIn + wcar[w] * glw;     // state entering chunk 32l
    double h = init0 * gl;              // homogeneous A0/B0 term at chunk 32l
    for (int i = 0; i < 32; ++i) {
      Ct[i * 256 + l] = A + h;
      A = m * A + St[i * 256 + l];
      h *= m;
    }
    __syncthreads();
  }
  if (l == 0) { acc[0] = 0.0; cnt[0] = 0u; }
}

// K3: 32 blocks x 256 threads; block b replays chunks [256b, 256b+256).
// R staged through padded LDS (conflict-free both directions). Last block
// finalizes the output via atomic counter (replaces k_fin + memset).
__global__ __launch_bounds__(256) void k_dsr(
    const float* __restrict__ R, const double* __restrict__ CAt,
    const double* __restrict__ CBt, double* __restrict__ acc,
    unsigned* __restrict__ cnt, float* __restrict__ out) {
  __shared__ float lr[256 * LPAD];      // 33.8 KB
  const int t  = threadIdx.x;
  const int j0 = blockIdx.x * 256;
  const float* Rb = R + (size_t)j0 * SCHUNK;
  #pragma unroll
  for (int q = 0; q < 32; ++q) {        // coalesced global -> padded LDS
    const int fi = q * 256 + t;         // flat row in this block's 8192 rows
    lr[((q * 8) + (t >> 5)) * LPAD + (t & 31)] = Rb[fi];
  }
  __syncthreads();

  const int c = j0 + t;
  double A = CAt[tpos(c)], B = CBt[tpos(c)];
  double sum = 0.0;
  #pragma unroll
  for (int k = 0; k < SCHUNK; ++k) {
    const double rv = (double)lr[t * LPAD + k];
    const double dA = ETA * (rv - A);
    const double dB = ETA * (rv * rv - B);
    double var = B - A * A;
    var = var > EPS ? var : EPS;
    sum += (B * dA - 0.5 * A * dB) / (var * sqrt(var));
    A += dA;
    B += dB;
  }
  sum += __shfl_xor(sum, 32, 64);
  sum += __shfl_xor(sum, 16, 64);
  sum += __shfl_xor(sum,  8, 64);
  sum += __shfl_xor(sum,  4, 64);
  sum += __shfl_xor(sum,  2, 64);
  sum += __shfl_xor(sum,  1, 64);
  __shared__ double red[4];
  const int wave = t >> 6, lane = t & 63;
  if (lane == 0) red[wave] = sum;
  __syncthreads();
  if (t == 0) {
    atomicAdd(acc, red[0] + red[1] + red[2] + red[3]);
    __threadfence();
    const unsigned old = atomicAdd(cnt, 1u);
    if (old == gridDim.x - 1) {
      const double v = atomicAdd(acc, 0.0);   // atomic read: all adds visible
      out[0] = (float)(-v / (double)BATCH);
    }
  }
}

extern "C" void kernel_launch(void* const* d_in, const int* in_sizes, int n_in,
                              void* d_out, int out_size, void* d_ws, size_t ws_size,
                              hipStream_t stream) {
  const float* W  = (const float*)d_in[0];
  const float* X  = (const float*)d_in[1];
  const float* A0 = (const float*)d_in[2];
  const float* B0 = (const float*)d_in[3];

  char* ws = (char*)d_ws;
  float*  R   = (float*)ws;                                // 1 MB
  double* SAt = (double*)(ws + (size_t)BATCH * 4);         // 64 KB each
  double* SBt = SAt + NSC;
  double* CAt = SBt + NSC;
  double* CBt = CAt + NSC;
  double* acc = CBt + NSC;
  unsigned* cnt = (unsigned*)(acc + 1);

  k_rows<<<NBLK, 256, 0, stream>>>(W, X, R, SAt, SBt);
  k_scan<<<1, 256, 0, stream>>>(SAt, SBt, A0, B0, CAt, CBt, acc, cnt);
  k_dsr<<<NSC / 256, 256, 0, stream>>>(R, CAt, CBt, acc, cnt, (float*)d_out);
}

// Round 4
// 58.971 us; speedup vs baseline: 1.3489x; 1.0039x over previous
//
#include <hip/hip_runtime.h>
#include <math.h>

#define BATCH     262144
#define NASSETS   128
#define TILE_ROWS 128                    // rows per K1 block
#define NBLK      (BATCH / TILE_ROWS)    // 2048
#define SCHUNK    32                     // scan / replay chunk
#define NSC       (BATCH / SCHUNK)       // 8192
#define ETA       0.01
#define CDECAY    0.99
#define EPS       1e-8
#define LPAD      33

// Transposed carry layout: chunk c stored at (c&31)*256 + (c>>5).
__device__ __forceinline__ int tpos(int c) { return (c & 31) * 256 + (c >> 5); }

__device__ __forceinline__ float dot4(float4 a, float4 b) {
  return a.x * b.x + a.y * b.y + a.z * b.z + a.w * b.w;
}

// K1: streaming dot products with an EXPLICIT register double-buffer.
// Batch b+1's 8 float4 loads are issued before batch b's LDS writes; the
// asm "memory" fence forbids the compiler from sinking the loads back down
// (R2 showed VGPR=32 => compiler had collapsed the pipeline to ~2 loads in
// flight; latency-bound at 5.1 TB/s).
__global__ __launch_bounds__(256) void k_rows(
    const float* __restrict__ W, const float* __restrict__ X,
    float* __restrict__ R, double* __restrict__ SAt, double* __restrict__ SBt) {
  __shared__ float part[TILE_ROWS * LPAD];
  __shared__ float hs[256];
  const int t   = threadIdx.x;
  const int blk = blockIdx.x;
  const float4* W4 = reinterpret_cast<const float4*>(W) + (size_t)blk * 4096;
  const float4* X4 = reinterpret_cast<const float4*>(X) + (size_t)blk * 4096;

  float4 w0 = W4[t];       float4 w1 = W4[t + 256];
  float4 w2 = W4[t + 512]; float4 w3 = W4[t + 768];
  float4 x0 = X4[t];       float4 x1 = X4[t + 256];
  float4 x2 = X4[t + 512]; float4 x3 = X4[t + 768];

  #pragma unroll
  for (int b = 0; b < 4; ++b) {
    float4 nw0, nw1, nw2, nw3, nx0, nx1, nx2, nx3;
    if (b < 3) {
      const int i1 = (b + 1) * 1024 + t;
      nw0 = W4[i1];       nw1 = W4[i1 + 256];
      nw2 = W4[i1 + 512]; nw3 = W4[i1 + 768];
      nx0 = X4[i1];       nx1 = X4[i1 + 256];
      nx2 = X4[i1 + 512]; nx3 = X4[i1 + 768];
    }
    asm volatile("" ::: "memory");      // loads above stay above these writes
    const int rb = b * 32 + (t >> 5), col = t & 31;
    part[(rb +  0) * LPAD + col] = dot4(w0, x0);
    part[(rb +  8) * LPAD + col] = dot4(w1, x1);
    part[(rb + 16) * LPAD + col] = dot4(w2, x2);
    part[(rb + 24) * LPAD + col] = dot4(w3, x3);
    if (b < 3) {
      w0 = nw0; w1 = nw1; w2 = nw2; w3 = nw3;
      x0 = nx0; x1 = nx1; x2 = nx2; x3 = nx3;
    }
  }
  __syncthreads();

  // Phase 2a: all 256 threads sum half a row each (row = t&127, half = t>>7)
  {
    const int row = t & 127, h = (t >> 7) * 16;
    float s = 0.f;
    #pragma unroll
    for (int j = 0; j < 16; ++j) s += part[row * LPAD + h + j];
    hs[t] = s;
  }
  __syncthreads();

  // Phase 2b: 128 threads finish rows + group carries via shfl (no pow).
  if (t < TILE_ROWS) {
    const float sum = hs[t] + hs[t + 128];
    R[(size_t)blk * TILE_ROWS + t] = sum;

    const int e = 31 - (t & 31);            // wgt = ETA * c^e via square-select
    const double c1 = CDECAY, c2 = c1*c1, c4 = c2*c2, c8 = c4*c4, c16 = c8*c8;
    double wgt = ETA;
    if (e & 1)  wgt *= c1;
    if (e & 2)  wgt *= c2;
    if (e & 4)  wgt *= c4;
    if (e & 8)  wgt *= c8;
    if (e & 16) wgt *= c16;
    const double r = (double)sum;
    double sA = wgt * r, sB = wgt * r * r;
    sA += __shfl_xor(sA, 16, 64); sB += __shfl_xor(sB, 16, 64);
    sA += __shfl_xor(sA,  8, 64); sB += __shfl_xor(sB,  8, 64);
    sA += __shfl_xor(sA,  4, 64); sB += __shfl_xor(sB,  4, 64);
    sA += __shfl_xor(sA,  2, 64); sB += __shfl_xor(sB,  2, 64);
    sA += __shfl_xor(sA,  1, 64); sB += __shfl_xor(sB,  1, 64);
    if ((t & 31) == 0) {
      const int c = blk * 4 + (t >> 5);
      SAt[tpos(c)] = sA;
      SBt[tpos(c)] = sB;
    }
  }
}

// K2: 512 threads, one block. Waves 0-3 scan the A-carries, waves 4-7 the
// B-carries in parallel. Within a half: lane l owns chunks [32l, 32l+32),
// coalesced via the transposed layout. Also zero-inits acc/cnt for k_dsr.
__global__ __launch_bounds__(512) void k_scan(
    const double* __restrict__ SAt, const double* __restrict__ SBt,
    const float* __restrict__ A0p, const float* __restrict__ B0p,
    double* __restrict__ CAt, double* __restrict__ CBt,
    double* __restrict__ acc, unsigned* __restrict__ cnt) {
  const int t    = threadIdx.x;
  const int half = t >> 8;              // 0 = A-scan, 1 = B-scan
  const int l    = t & 255;             // role within half
  const int lw   = l & 63, w = l >> 6;  // lane / wave within half
  __shared__ double wtot[8], wcar[8];

  const double* St = half ? SBt : SAt;
  double*       Ct = half ? CBt : CAt;
  const double init0 = half ? (double)B0p[0] : (double)A0p[0];

  double m = CDECAY;                    // -> c^32 (per-chunk factor)
  #pragma unroll
  for (int q = 0; q < 5; ++q) m = m * m;
  double g = m;                         // -> m^32 = c^1024 (per-lane factor)
  #pragma unroll
  for (int q = 0; q < 5; ++q) g = g * g;
  double F = g;                         // -> g^64 (per-wave factor)
  #pragma unroll
  for (int q = 0; q < 6; ++q) F = F * F;
  double glw = 1.0, gl = 1.0, p2 = g;   // g^lw and g^l via bit-select
  #pragma unroll
  for (int b = 0; b < 8; ++b) {
    if (lw & (1 << b)) glw *= p2;
    if (l  & (1 << b)) gl  *= p2;
    p2 = p2 * p2;
  }

  double y = 0.0;                       // compose this lane's 32 chunks
  for (int i = 0; i < 32; ++i) y = m * y + St[i * 256 + l];

  double s = y, f = g;                  // wave-level scan (factor g, squares)
  #pragma unroll
  for (int d = 1; d < 64; d <<= 1) {
    double u = __shfl_up(s, d, 64);
    if (lw >= d) s += f * u;
    f *= f;
  }
  if (lw == 63) wtot[half * 4 + w] = s;
  __syncthreads();
  if (l == 0) {
    double Wc = 0.0;
    for (int ww = 0; ww < 4; ++ww) {
      wcar[half * 4 + ww] = Wc;
      Wc = wtot[half * 4 + ww] + F * Wc;
    }
  }
  __syncthreads();
  double aIn = __shfl_up(s, 1, 64);
  if (lw == 0) aIn = 0.0;
  double A = aIn + wcar[half * 4 + w] * glw;   // state entering chunk 32l
  double h = init0 * gl;                        // homogeneous A0/B0 term
  for (int i = 0; i < 32; ++i) {
    Ct[i * 256 + l] = A + h;
    A = m * A + St[i * 256 + l];
    h *= m;
  }
  if (t == 0) { acc[0] = 0.0; cnt[0] = 0u; }
}

// K3: 64 blocks x 256 threads; block b replays chunks [128b, 128b+128).
// R staged through padded LDS (conflict-free both directions). Last block
// finalizes the output via atomic counter.
__global__ __launch_bounds__(256) void k_dsr(
    const float* __restrict__ R, const double* __restrict__ CAt,
    const double* __restrict__ CBt, double* __restrict__ acc,
    unsigned* __restrict__ cnt, float* __restrict__ out) {
  __shared__ float lr[128 * LPAD];      // 16.9 KB
  const int t  = threadIdx.x;
  const int j0 = blockIdx.x * 128;
  const float* Rb = R + (size_t)j0 * SCHUNK;   // 4096 floats per block
  #pragma unroll
  for (int q = 0; q < 16; ++q) {        // coalesced global -> padded LDS
    const int fi = q * 256 + t;
    lr[((q * 8) + (t >> 5)) * LPAD + (t & 31)] = Rb[fi];
  }
  __syncthreads();

  double sum = 0.0;
  if (t < 128) {
    const int c = j0 + t;
    double A = CAt[tpos(c)], B = CBt[tpos(c)];
    #pragma unroll
    for (int k = 0; k < SCHUNK; ++k) {
      const double rv = (double)lr[t * LPAD + k];
      const double dA = ETA * (rv - A);
      const double dB = ETA * (rv * rv - B);
      double var = B - A * A;
      var = var > EPS ? var : EPS;
      sum += (B * dA - 0.5 * A * dB) / (var * sqrt(var));
      A += dA;
      B += dB;
    }
  }
  sum += __shfl_xor(sum, 32, 64);
  sum += __shfl_xor(sum, 16, 64);
  sum += __shfl_xor(sum,  8, 64);
  sum += __shfl_xor(sum,  4, 64);
  sum += __shfl_xor(sum,  2, 64);
  sum += __shfl_xor(sum,  1, 64);
  __shared__ double red[4];
  const int wave = t >> 6, lane = t & 63;
  if (lane == 0) red[wave] = sum;
  __syncthreads();
  if (t == 0) {
    atomicAdd(acc, red[0] + red[1] + red[2] + red[3]);
    __threadfence();
    const unsigned old = atomicAdd(cnt, 1u);
    if (old == gridDim.x - 1) {
      const double v = atomicAdd(acc, 0.0);   // atomic read: all adds visible
      out[0] = (float)(-v / (double)BATCH);
    }
  }
}

extern "C" void kernel_launch(void* const* d_in, const int* in_sizes, int n_in,
                              void* d_out, int out_size, void* d_ws, size_t ws_size,
                              hipStream_t stream) {
  const float* W  = (const float*)d_in[0];
  const float* X  = (const float*)d_in[1];
  const float* A0 = (const float*)d_in[2];
  const float* B0 = (const float*)d_in[3];

  char* ws = (char*)d_ws;
  float*  R   = (float*)ws;                                // 1 MB
  double* SAt = (double*)(ws + (size_t)BATCH * 4);         // 64 KB each
  double* SBt = SAt + NSC;
  double* CAt = SBt + NSC;
  double* CBt = CAt + NSC;
  double* acc = CBt + NSC;
  unsigned* cnt = (unsigned*)(acc + 1);

  k_rows<<<NBLK, 256, 0, stream>>>(W, X, R, SAt, SBt);
  k_scan<<<1, 512, 0, stream>>>(SAt, SBt, A0, B0, CAt, CBt, acc, cnt);
  k_dsr<<<NSC / 128, 256, 0, stream>>>(R, CAt, CBt, acc, cnt, (float*)d_out);
}